// Round 4
// baseline (766.349 us; speedup 1.0000x reference)
//
#include <hip/hip_runtime.h>

#define SEQ   2048
#define BATCH 4096
#define HD    32

// ---------------- fast device math ----------------
__device__ __forceinline__ float exp2_fast(float a) {
#if __has_builtin(__builtin_amdgcn_exp2f)
    return __builtin_amdgcn_exp2f(a);
#else
    return exp2f(a);
#endif
}

__device__ __forceinline__ float rcp_fast(float a) {
#if __has_builtin(__builtin_amdgcn_rcpf)
    return __builtin_amdgcn_rcpf(a);
#else
    return 1.0f / a;
#endif
}

// tanh(x) = sign(x) * (1 - e^{-2|x|}) / (1 + e^{-2|x|})
__device__ __forceinline__ float fast_tanh(float v) {
    float ax = fabsf(v);
    float e  = exp2_fast(ax * -2.8853900817779268f);
    float r  = (1.0f - e) * rcp_fast(1.0f + e);
    return copysignf(r, v);
}

// DPP lane exchange, bound_ctrl=1 + full masks: foldable by GCNDPPCombine into
// the consuming VOP2 (v_fmac_f32_dpp / v_add_f32_dpp). All lanes always active
// at call sites, so bound_ctrl semantics never bite.
// 0xB1 quad_perm[1,0,3,2]=xor-1 ; 0x4E quad_perm[2,3,0,1]=xor-2
// 0x1B quad_perm[3,2,1,0]=xor-3 ; 0x141 row_half_mirror=xor-7 ; 0x140 row_mirror=xor-15
template <int CTRL>
__device__ __forceinline__ float dpp_b(float v) {
    return __int_as_float(
        __builtin_amdgcn_update_dpp(0, __float_as_int(v), CTRL, 0xF, 0xF, true));
}

// ds_swizzle xor-16 fallback (verified r1/r2).
__device__ __forceinline__ float swz_xor16(float v) {
    return __int_as_float(__builtin_amdgcn_ds_swizzle(__float_as_int(v), 0x401F));
}

#if __has_builtin(__builtin_amdgcn_permlane16_swap)
#define HAVE_PL16 1
typedef unsigned int uint2v __attribute__((ext_vector_type(2)));
#endif

// value held by lane i^16 (cross 16-row exchange), as a VALU op when available.
__device__ __forceinline__ float xchg16(float v, int halfbit) {
#ifdef HAVE_PL16
    uint2v r = __builtin_amdgcn_permlane16_swap(__float_as_uint(v), __float_as_uint(v),
                                                false, false);
    const float even_dup = __uint_as_float(r.x);   // lane i -> v[i & ~16]
    const float odd_dup  = __uint_as_float(r.y);   // lane i -> v[i |  16]
    return halfbit ? even_dup : odd_dup;           // = v[i ^ 16]
#else
    (void)halfbit;
    return swz_xor16(v);
#endif
}

// sum of v over lanes {i, i^16} (v must be 16-row-uniform for a full 32-sum).
__device__ __forceinline__ float xsum16(float v) {
#ifdef HAVE_PL16
    uint2v r = __builtin_amdgcn_permlane16_swap(__float_as_uint(v), __float_as_uint(v),
                                                false, false);
    return __uint_as_float(r.x) + __uint_as_float(r.y);   // v[i&~16] + v[i|16]
#else
    return v + swz_xor16(v);
#endif
}

// 16 FMA slots over one 16-k half. Slot eo multiplies h_{kb + (L^eo)}.
// Sources: HS(eo 0-3), C7=HS[^7](eo 4-7), C8=HS[^8](eo 8-11), C15=HS[^15](eo 12-15),
// with single-use quad-perm DPPs so each folds into its v_fmac.
#define ACCH(P0, P1, HS, C7, C8, C15, W)             \
    P0 = fmaf((HS),            W[0],  P0);           \
    P0 = fmaf(dpp_b<0xB1>(HS), W[1],  P0);           \
    P0 = fmaf(dpp_b<0x4E>(HS), W[2],  P0);           \
    P0 = fmaf(dpp_b<0x1B>(HS), W[3],  P0);           \
    P0 = fmaf(dpp_b<0x1B>(C7), W[4],  P0);           \
    P0 = fmaf(dpp_b<0x4E>(C7), W[5],  P0);           \
    P0 = fmaf(dpp_b<0xB1>(C7), W[6],  P0);           \
    P0 = fmaf((C7),            W[7],  P0);           \
    P1 = fmaf((C8),            W[8],  P1);           \
    P1 = fmaf(dpp_b<0xB1>(C8), W[9],  P1);           \
    P1 = fmaf(dpp_b<0x4E>(C8), W[10], P1);           \
    P1 = fmaf(dpp_b<0x1B>(C8), W[11], P1);           \
    P1 = fmaf(dpp_b<0x1B>(C15),W[12], P1);           \
    P1 = fmaf(dpp_b<0x4E>(C15),W[13], P1);           \
    P1 = fmaf(dpp_b<0xB1>(C15),W[14], P1);           \
    P1 = fmaf((C15),           W[15], P1);

// ---------------- kernel ----------------
// 32 lanes/element (2 elems/wave, 8/block, 2 blocks/CU -> 2 waves/SIMD).
// Lane i owns FULL row i of W_hh (32 FMAs). h_j lives in lane j. The 16 h of
// the lane's own DPP row arrive via foldable DPP reads; the other 16-row's h
// arrive via ONE v_permlane16_swap + cndmask (VALU, ~8 cyc) instead of the
// 120-cyc ds_swizzle. No LDS anywhere; no partial-sum exchange in the chain.
__global__
__attribute__((amdgpu_flat_work_group_size(256, 256)))
__attribute__((amdgpu_waves_per_eu(2, 2)))
void rnn_elman_kernel(
    const float* __restrict__ x, const float* __restrict__ hidden,
    const float* __restrict__ W_ih, const float* __restrict__ b_ih,
    const float* __restrict__ W_hh, const float* __restrict__ b_hh,
    const float* __restrict__ W_fc, const float* __restrict__ b_fc,
    float* __restrict__ out)
{
    const int tid  = threadIdx.x;
    const int i    = tid & 31;        // row owned by this lane
    const int L    = i & 15;          // position within 16-lane DPP row
    const int half = (i >> 4) & 1;    // which 16-row of the 32-lane group
    const int eb   = tid >> 5;        // element within block (0..7)
    const int e    = blockIdx.x * 8 + eb;

    // ---- weights: full row i, halves separate, columns xor-permuted ----
    float wa[16], wb[16];
    {
        const float* Wrow = W_hh + i * HD;
        const int kb_own = 16 * half;        // k's resident in own DPP row
        const int kb_oth = 16 - kb_own;      // k's resident in the other row
        #pragma unroll
        for (int eo = 0; eo < 16; ++eo) {
            wa[eo] = Wrow[kb_own + (L ^ eo)];
            wb[eo] = Wrow[kb_oth + (L ^ eo)];
        }
    }
    const float wih  = W_ih[i];
    const float bias = b_ih[i] + b_hh[i];
    const float wfc  = W_fc[i];
    const float bfc  = b_fc[0];

    // ---- init: h_i lives in lane i ----
    float h = hidden[e * HD + i];

    // ---- x prefetch pipe (distance 4) ----
    const float* __restrict__ xe = x + e;
    float xq0 = xe[0 * BATCH];
    float xq1 = xe[1 * BATCH];
    float xq2 = xe[2 * BATCH];
    float xq3 = xe[3 * BATCH];

    #pragma unroll 4
    for (int t = 0; t < SEQ; ++t) {
        const float xv = xq0;
        xq0 = xq1; xq1 = xq2; xq2 = xq3;
        {
            int tt = t + 4; tt = tt < SEQ ? tt : SEQ - 1;   // uniform clamp
            xq3 = xe[tt * BATCH];
        }

        // ---- other 16-row's h via permlane16_swap (VALU) ----
        const float hoth = xchg16(h, half);    // = h[i^16] base for other half

        // ---- gather companions (multi-use movs, 3 per source) ----
        const float c7  = dpp_b<0x141>(h);
        const float c15 = dpp_b<0x140>(h);
        const float c8  = dpp_b<0x141>(c15);   // ^15 then ^7 = ^8
        const float o7  = dpp_b<0x141>(hoth);
        const float o15 = dpp_b<0x140>(hoth);
        const float o8  = dpp_b<0x141>(o15);

        // ---- full-row dot: 4 chains of depth 8/9 ----
        float a0 = fmaf(xv, wih, bias);
        float a1 = 0.f, b0 = 0.f, b1 = 0.f;
        ACCH(a0, a1, h,    c7, c8, c15, wa);   // own-row-resident k half
        ACCH(b0, b1, hoth, o7, o8, o15, wb);   // other-row-resident k half

        const float z = (a0 + a1) + (b0 + b1);
        h = fast_tanh(z);

        // ---- output projection: foldable add_dpp tree + permlane cross-sum ----
        float u = h * wfc;
        u += dpp_b<0xB1>(u);     // xor-1
        u += dpp_b<0x4E>(u);     // xor-2
        u += dpp_b<0x141>(u);    // quad-pair combine
        u += dpp_b<0x140>(u);    // 16-row total
        const float tot = xsum16(u) + bfc;     // full 32-row sum, all lanes
        if (i == 0) out[t * BATCH + e] = tot;
    }
}

// ---------------- launch ----------------
extern "C" void kernel_launch(void* const* d_in, const int* in_sizes, int n_in,
                              void* d_out, int out_size, void* d_ws, size_t ws_size,
                              hipStream_t stream) {
    const float* x    = (const float*)d_in[0];
    const float* hid  = (const float*)d_in[1];
    const float* W_ih = (const float*)d_in[2];
    const float* b_ih = (const float*)d_in[3];
    const float* W_hh = (const float*)d_in[4];
    const float* b_hh = (const float*)d_in[5];
    const float* W_fc = (const float*)d_in[6];
    const float* b_fc = (const float*)d_in[7];
    float* out = (float*)d_out;

    dim3 grid(BATCH / 8);    // 512 blocks -> 2 blocks/CU
    dim3 block(256);         // 8 elements/block; 8 waves/CU, 2/SIMD
    rnn_elman_kernel<<<grid, block, 0, stream>>>(x, hid, W_ih, b_ih, W_hh, b_hh,
                                                 W_fc, b_fc, out);
}

// Round 5
// 576.485 us; speedup vs baseline: 1.3293x; 1.3293x over previous
//
#include <hip/hip_runtime.h>

#define SEQ   2048
#define BATCH 4096
#define HD    32

typedef float f32x2 __attribute__((ext_vector_type(2)));
typedef float f32x4 __attribute__((ext_vector_type(4)));

// ---------------- fast device math ----------------
__device__ __forceinline__ float exp2_fast(float a) {
#if __has_builtin(__builtin_amdgcn_exp2f)
    return __builtin_amdgcn_exp2f(a);
#else
    return exp2f(a);
#endif
}

__device__ __forceinline__ float rcp_fast(float a) {
#if __has_builtin(__builtin_amdgcn_rcpf)
    return __builtin_amdgcn_rcpf(a);
#else
    return 1.0f / a;
#endif
}

// tanh(x) = sign(x) * (1 - e^{-2|x|}) / (1 + e^{-2|x|})
__device__ __forceinline__ float fast_tanh(float v) {
    float ax = fabsf(v);
    float e  = exp2_fast(ax * -2.8853900817779268f);
    float r  = (1.0f - e) * rcp_fast(1.0f + e);
    return copysignf(r, v);
}

// DPP exchange (old=0, bound_ctrl=0, full masks) — exact r2 helper, HW-verified.
// 0xB1 quad_perm[1,0,3,2]=xor-1 ; 0x4E quad_perm[2,3,0,1]=xor-2
// 0x141 row_half_mirror ; 0x140 row_mirror
template <int CTRL>
__device__ __forceinline__ float dpp_x(float v) {
    return __int_as_float(
        __builtin_amdgcn_update_dpp(0, __float_as_int(v), CTRL, 0xF, 0xF, false));
}

// ds_swizzle xor-16 within each 32-lane group (HW-verified r1/r2).
__device__ __forceinline__ float swz_xor16(float v) {
    return __int_as_float(__builtin_amdgcn_ds_swizzle(__float_as_int(v), 0x401F));
}

// ---------------- kernel ----------------
// r2's HW-verified decomposition + packed-FP32 matvec.
// 32 lanes/element: lane i, ks=i&3 owns k-slice [ks*8, ks*8+8) and accumulates
// rows (i&~3)|(ks^j), j=0..3, as 16 v_pk_fma_f32 (float2). Cross-slice reduce
// via 3 DPP xor-adds leaves row i's z in lane i. h broadcast via LDS
// (1x ds_write_b32 + 2x ds_read_b128 per lane). 512-thread blocks so each
// block owns a 64-B line of every x row (kills the 2x FETCH over-read).
// waves_per_eu(2,2): stops the register allocator from squeezing below the
// 32 resident weight VGPRs (r2's VGPR=32 reload pathology).
__global__
__attribute__((amdgpu_flat_work_group_size(512, 512)))
__attribute__((amdgpu_waves_per_eu(2, 2)))
void rnn_elman_kernel(
    const float* __restrict__ x, const float* __restrict__ hidden,
    const float* __restrict__ W_ih, const float* __restrict__ b_ih,
    const float* __restrict__ W_hh, const float* __restrict__ b_hh,
    const float* __restrict__ W_fc, const float* __restrict__ b_fc,
    float* __restrict__ out)
{
    __shared__ float sh[16 * 36];    // 16 elements/block, padded stride 36

    const int tid = threadIdx.x;
    const int i   = tid & 31;        // lane within element group == owned row
    const int ks  = i & 3;           // k-slice index
    const int eb  = tid >> 5;        // element within block (0..15)
    const int e   = blockIdx.x * 16 + eb;

    // ---- weights: 4 xor-permuted rows x 8-k slice, packed as float2 ----
    f32x2 wv[4][4];
    {
        const int rbase = i & ~3;
        #pragma unroll
        for (int j = 0; j < 4; ++j) {
            const float* R = W_hh + (rbase | (ks ^ j)) * HD + ks * 8;
            #pragma unroll
            for (int m = 0; m < 4; ++m) wv[j][m] = f32x2{R[2 * m], R[2 * m + 1]};
        }
    }
    const float wih  = W_ih[i];
    const float bias = b_ih[i] + b_hh[i];
    const float wfc  = W_fc[i];
    const float bfc  = b_fc[0];

    float* slot = sh + eb * 36;
    const f32x4* rd = reinterpret_cast<const f32x4*>(slot + ks * 8);

    // ---- init hidden state into LDS, pull my k-slice ----
    slot[i] = hidden[e * HD + i];
    __builtin_amdgcn_wave_barrier();
    f32x2 h2[4];
    {
        const f32x4 a = rd[0], b = rd[1];
        h2[0] = f32x2{a.x, a.y}; h2[1] = f32x2{a.z, a.w};
        h2[2] = f32x2{b.x, b.y}; h2[3] = f32x2{b.z, b.w};
    }

    // ---- x prefetch pipe (distance 4) ----
    const float* __restrict__ xe = x + e;
    float xq0 = xe[(size_t)0 * BATCH];
    float xq1 = xe[(size_t)1 * BATCH];
    float xq2 = xe[(size_t)2 * BATCH];
    float xq3 = xe[(size_t)3 * BATCH];

    #pragma unroll 4
    for (int t = 0; t < SEQ; ++t) {
        const float xv = xq0;
        xq0 = xq1; xq1 = xq2; xq2 = xq3;
        {
            int tt = t + 4; tt = tt < SEQ ? tt : SEQ - 1;    // uniform clamp
            xq3 = xe[(size_t)tt * BATCH];
        }

        // ---- packed matvec: 4 rows x 4 pk_fma (fp-contract -> v_pk_fma_f32) ----
        f32x2 p0 = f32x2{fmaf(xv, wih, bias), 0.f};   // row i seed in p0.x
        f32x2 p1 = f32x2{0.f, 0.f};
        f32x2 p2 = f32x2{0.f, 0.f};
        f32x2 p3 = f32x2{0.f, 0.f};
        #pragma unroll
        for (int m = 0; m < 4; ++m) {
            const f32x2 hm = h2[m];
            p0 += wv[0][m] * hm;
            p1 += wv[1][m] * hm;
            p2 += wv[2][m] * hm;
            p3 += wv[3][m] * hm;
        }
        const float P0 = p0.x + p0.y;
        const float P1 = p1.x + p1.y;
        const float P2 = p2.x + p2.y;
        const float P3 = p3.x + p3.y;

        // ---- cross-slice reduce (r2-verified): lane i ends with z of row i ----
        const float q0 = P0 + dpp_x<0xB1>(P1);   // xor-1
        const float q1 = P2 + dpp_x<0xB1>(P3);   // xor-1
        const float z  = q0 + dpp_x<0x4E>(q1);   // xor-2
        const float h  = fast_tanh(z);

        // ---- output tree first: its swizzle can then wait at lgkmcnt>0 ----
        float u = h * wfc;
        u += dpp_x<0xB1>(u);     // xor-1
        u += dpp_x<0x4E>(u);     // xor-2
        u += dpp_x<0x141>(u);    // quad-pair combine
        u += dpp_x<0x140>(u);    // 16-row total
        const float usw = swz_xor16(u);   // other half's total

        // ---- publish own h, refetch k-slice ----
        slot[i] = h;
        __builtin_amdgcn_wave_barrier();
        const f32x4 a = rd[0], b = rd[1];
        h2[0] = f32x2{a.x, a.y}; h2[1] = f32x2{a.z, a.w};
        h2[2] = f32x2{b.x, b.y}; h2[3] = f32x2{b.z, b.w};

        if ((tid & 31) == 0) out[(size_t)t * BATCH + e] = u + usw + bfc;
    }
}

// ---------------- launch ----------------
extern "C" void kernel_launch(void* const* d_in, const int* in_sizes, int n_in,
                              void* d_out, int out_size, void* d_ws, size_t ws_size,
                              hipStream_t stream) {
    const float* x    = (const float*)d_in[0];
    const float* hid  = (const float*)d_in[1];
    const float* W_ih = (const float*)d_in[2];
    const float* b_ih = (const float*)d_in[3];
    const float* W_hh = (const float*)d_in[4];
    const float* b_hh = (const float*)d_in[5];
    const float* W_fc = (const float*)d_in[6];
    const float* b_fc = (const float*)d_in[7];
    float* out = (float*)d_out;

    dim3 grid(BATCH / 16);   // 256 blocks -> 1 block/CU
    dim3 block(512);         // 16 elements/block, 8 waves -> 2 waves/SIMD
    rnn_elman_kernel<<<grid, block, 0, stream>>>(x, hid, W_ih, b_ih, W_hh, b_hh,
                                                 W_fc, b_fc, out);
}